// Round 1
// baseline (1585.468 us; speedup 1.0000x reference)
//
#include <hip/hip_runtime.h>
#include <hip/hip_bf16.h>
#include <math.h>

// ---------------------------------------------------------------------------
// GAT: 2x GATConv(heads=1) + global mean pool + FC(64->2)
// R15 = structural rewrite of the aggregation path.
//   Old: per-node CSR gather (8 lanes/node) -> random 128B gathers of h16,
//        172MB L2-miss traffic/dispatch, VALU 25%, latency-bound (57.4us).
//   New: * partition to 128-node dst buckets (782 buckets)
//        * sort_bucket: in-LDS counting sort of each bucket's edges by src>>9
//        * gat_aggregate2: 1 block/bucket, edge-parallel in src-sorted order,
//          LDS acc[128][65] f32 via ds_add_f32 (col 64 = softmax denom),
//          self-loop folded into epilogue. All 782 blocks resident in one
//          round -> chip-synchronized linear sweep of h16 -> L2-hot front.
//        * build_csr DELETED (no CSR needed at all).
// GEMM + pool_fc byte-identical to R14.
// ---------------------------------------------------------------------------

#define NPB 128          // nodes per dst bucket
#define EPB 4096         // edges per partition block (256 thr x 16)
#define PSTRIDE 2368     // slots per bucket (lambda=2046, +7 sigma)
#define ACCW 65          // acc row: 64 feats + wsum; 65 -> bank = dl+8l+k
#define XPAD 68          // xs leading-dim pad (node_gemm, unchanged)

__device__ __forceinline__ unsigned int f2bf(float v) {
    unsigned int b = __float_as_uint(v);
    b += 0x7FFFu + ((b >> 16) & 1u);   // round-to-nearest-even
    return b >> 16;
}

// --- init: zero bucket cursors ----------------------------------------------
__global__ __launch_bounds__(256) void init_all(int* __restrict__ bcur, int NB) {
    int i = blockIdx.x * 256 + threadIdx.x;
    if (i < NB) bcur[i] = 0;
}

// --- partition edges into fixed-stride dst-buckets (packed uint32) ----------
__global__ __launch_bounds__(256) void partition(const int* __restrict__ ei,
                                                 int E, int NB,
                                                 int* __restrict__ bcur,
                                                 unsigned int* __restrict__ pairs) {
    __shared__ int h[1024];
    __shared__ int hb[1024];
    int t = threadIdx.x;
    for (int i = t; i < 1024; i += 256) h[i] = 0;
    __syncthreads();
    int i0 = blockIdx.x * EPB;
    unsigned int val[16];
    int bk[16], r[16];
#pragma unroll
    for (int k = 0; k < 16; k++) {
        int i = i0 + k * 256 + t;
        bk[k] = -1;
        if (i < E) {
            int s = ei[i];
            int d = ei[E + i];
            bk[k] = d >> 7;
            val[k] = (unsigned)s | ((unsigned)(d & 127) << 24);
            r[k] = atomicAdd(&h[bk[k]], 1);
        }
    }
    __syncthreads();
    for (int b = t; b < NB; b += 256)
        hb[b] = h[b] ? atomicAdd(&bcur[b], h[b]) : 0;
    __syncthreads();
#pragma unroll
    for (int k = 0; k < 16; k++) {
        if (bk[k] < 0) continue;
        int pos = hb[bk[k]] + r[k];
        if (pos < PSTRIDE)                 // overflow guard (stat. impossible)
            pairs[(size_t)bk[k] * PSTRIDE + pos] = val[k];
    }
}

// --- coarse counting sort of each bucket's edges by src>>9 (512-node bins) --
// Purpose: all aggregate blocks sweep h16 in the same ascending-src order ->
// temporally-aligned fronts -> the active window stays L2-resident.
__global__ __launch_bounds__(256) void sort_bucket(const unsigned int* __restrict__ pairs,
                                                   const int* __restrict__ bcur,
                                                   unsigned int* __restrict__ pairs2) {
    int b = blockIdx.x, t = threadIdx.x;
    int cnt = min(bcur[b], PSTRIDE);
    __shared__ unsigned int Q[PSTRIDE];   // 9.25 KB
    __shared__ int hist[256];
    __shared__ int cur[256];
    hist[t] = 0;
    __syncthreads();
    const unsigned int* pb = pairs + (size_t)b * PSTRIDE;
    for (int j = t; j < cnt; j += 256)
        atomicAdd(&hist[(pb[j] & 0xFFFFFFu) >> 9], 1);   // key <= 195
    __syncthreads();
    int v = hist[t];
    cur[t] = v;
    __syncthreads();
    for (int o = 1; o < 256; o <<= 1) {
        int u = (t >= o) ? cur[t - o] : 0;
        __syncthreads();
        cur[t] += u;
        __syncthreads();
    }
    cur[t] -= v;                          // exclusive base -> cursor
    __syncthreads();
    for (int j = t; j < cnt; j += 256) {
        unsigned int p = pb[j];
        int pos = atomicAdd(&cur[(p & 0xFFFFFFu) >> 9], 1);
        Q[pos] = p;
    }
    __syncthreads();
    unsigned int* ob = pairs2 + (size_t)b * PSTRIDE;
    for (int j = t; j < cnt; j += 256) ob[j] = Q[j];     // coalesced
}

// --- tiled node GEMM: 64 nodes x 64 cols per block, 4x4 per thread ----------
template <int IN_DIM>
__global__ __launch_bounds__(256) void node_gemm(const float* __restrict__ x,
                                                 const float* __restrict__ W,
                                                 const float* __restrict__ a_src,
                                                 const float* __restrict__ a_dst,
                                                 const float* __restrict__ bias_in,
                                                 float slope_in,
                                                 unsigned short* __restrict__ h16,
                                                 float* __restrict__ al_s,
                                                 float* __restrict__ al_d,
                                                 int n) {
    __shared__ float Ws[IN_DIM * 64];
    __shared__ float xs[IN_DIM][XPAD];
    int t = threadIdx.x;
    int nbase = blockIdx.x * 64;

    for (int idx = t; idx < IN_DIM * 16; idx += 256)
        ((float4*)Ws)[idx] = ((const float4*)W)[idx];
    const float* xb = x + (size_t)nbase * IN_DIM;
    int lim = min(64, n - nbase) * IN_DIM;
    for (int idx = t; idx < 64 * IN_DIM; idx += 256) {
        int node = idx / IN_DIM;
        int k = idx - node * IN_DIM;
        float v = 0.0f;
        if (idx < lim) {
            v = xb[idx];                       // contiguous, fully coalesced
            if (bias_in) {
                v += bias_in[k];
                v = (v >= 0.0f) ? v : slope_in * v;
            }
        }
        xs[k][node] = v;
    }
    __syncthreads();

    int cg = t & 15;    // col group: cols 4cg..4cg+3
    int ng = t >> 4;    // node group: nodes 4ng..4ng+3
    float acc[4][4] = {};
#pragma unroll 8
    for (int k = 0; k < IN_DIM; k++) {
        float4 xv = *(const float4*)&xs[k][ng * 4];
        float4 wv = *(const float4*)&Ws[k * 64 + cg * 4];
        float xa[4] = {xv.x, xv.y, xv.z, xv.w};
        float wa[4] = {wv.x, wv.y, wv.z, wv.w};
#pragma unroll
        for (int i = 0; i < 4; i++)
#pragma unroll
            for (int j = 0; j < 4; j++)
                acc[i][j] += xa[i] * wa[j];
    }

    float4 as4 = *(const float4*)(a_src + cg * 4);
    float4 ad4 = *(const float4*)(a_dst + cg * 4);
#pragma unroll
    for (int i = 0; i < 4; i++) {
        int node = nbase + ng * 4 + i;
        if (node < n) {
            uint2 p;
            p.x = f2bf(acc[i][0]) | (f2bf(acc[i][1]) << 16);
            p.y = f2bf(acc[i][2]) | (f2bf(acc[i][3]) << 16);
            *(uint2*)(h16 + (size_t)node * 64 + cg * 4) = p;
        }
        float vs = acc[i][0] * as4.x + acc[i][1] * as4.y +
                   acc[i][2] * as4.z + acc[i][3] * as4.w;
        float vd = acc[i][0] * ad4.x + acc[i][1] * ad4.y +
                   acc[i][2] * ad4.z + acc[i][3] * ad4.w;
#pragma unroll
        for (int o = 8; o; o >>= 1) {
            vs += __shfl_xor(vs, o);
            vd += __shfl_xor(vd, o);
        }
        if (cg == 0 && node < n) { al_s[node] = vs; al_d[node] = vd; }
    }
}

// --- aggregate v2: 1 block/bucket, edge-parallel sorted sweep, LDS acc ------
__device__ __forceinline__ void bf8_atomic(float* a, uint4 q, float w) {
    atomicAdd(a + 0, w * __uint_as_float(q.x << 16));
    atomicAdd(a + 1, w * __uint_as_float(q.x & 0xFFFF0000u));
    atomicAdd(a + 2, w * __uint_as_float(q.y << 16));
    atomicAdd(a + 3, w * __uint_as_float(q.y & 0xFFFF0000u));
    atomicAdd(a + 4, w * __uint_as_float(q.z << 16));
    atomicAdd(a + 5, w * __uint_as_float(q.z & 0xFFFF0000u));
    atomicAdd(a + 6, w * __uint_as_float(q.w << 16));
    atomicAdd(a + 7, w * __uint_as_float(q.w & 0xFFFF0000u));
}

__global__ __launch_bounds__(256) void gat_aggregate2(const unsigned int* __restrict__ pairs,
                                                      const int* __restrict__ bcur,
                                                      const float* __restrict__ als,
                                                      const float* __restrict__ ald,
                                                      const unsigned short* __restrict__ h16,
                                                      float* __restrict__ hout, int n) {
    int b = blockIdx.x, t = threadIdx.x;
    int d0 = b << 7;
    int nb = min(NPB, n - d0);
    int cnt = min(bcur[b], PSTRIDE);
    __shared__ float acc[NPB * ACCW];     // 33.3 KB -> 4 blocks/CU
    __shared__ float alds[NPB];
    for (int i = t; i < NPB * ACCW; i += 256) acc[i] = 0.0f;
    if (t < NPB) alds[t] = (t < nb) ? ald[d0 + t] : 0.0f;
    __syncthreads();

    int g = t >> 3, lane = t & 7;          // 32 edge-groups, 8 lanes/edge
    const unsigned short* hb = h16 + lane * 8;
    const unsigned int* pb = pairs + (size_t)b * PSTRIDE;

    int j = g;
    for (; j + 32 < cnt; j += 64) {        // unroll 2: 2 gathers in flight
        unsigned int p0 = pb[j], p1 = pb[j + 32];
        int s0 = p0 & 0xFFFFFFu, s1 = p1 & 0xFFFFFFu;
        int dl0 = p0 >> 24, dl1 = p1 >> 24;
        uint4 q0 = *(const uint4*)(hb + (size_t)s0 * 64);
        uint4 q1 = *(const uint4*)(hb + (size_t)s1 * 64);
        float e0 = als[s0] + alds[dl0];
        float e1 = als[s1] + alds[dl1];
        e0 = (e0 >= 0.0f) ? e0 : 0.2f * e0;
        e1 = (e1 >= 0.0f) ? e1 : 0.2f * e1;
        float w0 = __expf(e0), w1 = __expf(e1);
        float* a0 = acc + dl0 * ACCW + lane * 8;
        float* a1 = acc + dl1 * ACCW + lane * 8;
        bf8_atomic(a0, q0, w0);
        if (lane == 0) atomicAdd(acc + dl0 * ACCW + 64, w0);
        bf8_atomic(a1, q1, w1);
        if (lane == 0) atomicAdd(acc + dl1 * ACCW + 64, w1);
    }
    for (; j < cnt; j += 32) {
        unsigned int p = pb[j];
        int s = p & 0xFFFFFFu;
        int dl = p >> 24;
        uint4 q = *(const uint4*)(hb + (size_t)s * 64);
        float e = als[s] + alds[dl];
        e = (e >= 0.0f) ? e : 0.2f * e;
        float w = __expf(e);
        float* a = acc + dl * ACCW + lane * 8;
        bf8_atomic(a, q, w);
        if (lane == 0) atomicAdd(acc + dl * ACCW + 64, w);
    }
    __syncthreads();

    // epilogue: fold self-loop, normalize, write out (coalesced)
    for (int d = g; d < nb; d += 32) {
        int node = d0 + d;
        float e = als[node] + alds[d];
        e = (e >= 0.0f) ? e : 0.2f * e;
        float ws = __expf(e);
        uint4 q = *(const uint4*)(h16 + (size_t)node * 64 + lane * 8);
        float inv = 1.0f / (acc[d * ACCW + 64] + ws + 1e-16f);
        const float* ar = acc + d * ACCW + lane * 8;
        float o0 = (ar[0] + ws * __uint_as_float(q.x << 16)) * inv;
        float o1 = (ar[1] + ws * __uint_as_float(q.x & 0xFFFF0000u)) * inv;
        float o2 = (ar[2] + ws * __uint_as_float(q.y << 16)) * inv;
        float o3 = (ar[3] + ws * __uint_as_float(q.y & 0xFFFF0000u)) * inv;
        float o4 = (ar[4] + ws * __uint_as_float(q.z << 16)) * inv;
        float o5 = (ar[5] + ws * __uint_as_float(q.z & 0xFFFF0000u)) * inv;
        float o6 = (ar[6] + ws * __uint_as_float(q.w << 16)) * inv;
        float o7 = (ar[7] + ws * __uint_as_float(q.w & 0xFFFF0000u)) * inv;
        float* op = hout + (size_t)node * 64 + lane * 8;
        *(float4*)op = make_float4(o0, o1, o2, o3);
        *(float4*)(op + 4) = make_float4(o4, o5, o6, o7);
    }
}

// --- fused pool + FC: one block per graph, binary-search batch bounds -------
__global__ __launch_bounds__(256) void pool_fc(const float* __restrict__ hout,
                                               const float* __restrict__ b2,
                                               const int* __restrict__ batch,
                                               const float* __restrict__ fcW,
                                               const float* __restrict__ fcb,
                                               float* __restrict__ out, int n) {
    int g = blockIdx.x;
    int t = threadIdx.x;
    __shared__ int sLo, sHi;
    __shared__ float red[4][64];
    if (t == 0) {
        int lo = 0, hi = n;
        while (lo < hi) { int m = (lo + hi) >> 1; if (batch[m] < g) lo = m + 1; else hi = m; }
        sLo = lo;
    } else if (t == 64) {
        int lo = 0, hi = n;
        while (lo < hi) { int m = (lo + hi) >> 1; if (batch[m] < g + 1) lo = m + 1; else hi = m; }
        sHi = lo;
    }
    __syncthreads();
    int lo = sLo, hi = sHi;
    int wv = t >> 6, lane = t & 63;
    float acc = 0.0f;
    for (int node = lo + wv; node < hi; node += 4)
        acc += hout[(size_t)node * 64 + lane];
    red[wv][lane] = acc;
    __syncthreads();
    if (wv == 0) {
        float c = (float)(hi - lo);
        float s = red[0][lane] + red[1][lane] + red[2][lane] + red[3][lane];
        s += c * b2[lane];
        float cd = (c > 1.0f) ? c : 1.0f;
        float p = s / cd;
        float s0 = p * fcW[lane * 2 + 0];
        float s1 = p * fcW[lane * 2 + 1];
#pragma unroll
        for (int o = 32; o; o >>= 1) {
            s0 += __shfl_xor(s0, o);
            s1 += __shfl_xor(s1, o);
        }
        if (lane == 0) {
            out[g * 2 + 0] = s0 + fcb[0];
            out[g * 2 + 1] = s1 + fcb[1];
        }
    }
}

extern "C" void kernel_launch(void* const* d_in, const int* in_sizes, int n_in,
                              void* d_out, int out_size, void* d_ws, size_t ws_size,
                              hipStream_t stream) {
    const float* x    = (const float*)d_in[0];
    const int*   ei   = (const int*)d_in[1];
    const int*   batch= (const int*)d_in[2];
    const float* W1   = (const float*)d_in[3];
    const float* as1  = (const float*)d_in[4];
    const float* ad1  = (const float*)d_in[5];
    const float* b1   = (const float*)d_in[6];
    const float* W2   = (const float*)d_in[7];
    const float* as2  = (const float*)d_in[8];
    const float* ad2  = (const float*)d_in[9];
    const float* b2   = (const float*)d_in[10];
    const float* fcW  = (const float*)d_in[11];
    const float* fcb  = (const float*)d_in[12];
    float* out = (float*)d_out;

    const int N = in_sizes[2];       // 100000
    const int E = in_sizes[1] / 2;   // 1600000
    const int G = out_size / 2;      // 256
    const int NB = (N + NPB - 1) / NPB;   // 782 buckets

    // ws layout (~54 MB): bufO | pairs | pairs2 | als | ald | bcur | bufH16
    float* ws     = (float*)d_ws;
    float* bufO   = ws;                                          // 25.6 MB
    unsigned int* pairs  = (unsigned int*)(bufO + (size_t)N * 64);   // 7.4 MB
    unsigned int* pairs2 = pairs + (size_t)NB * PSTRIDE;             // 7.4 MB
    float* als    = (float*)(pairs2 + (size_t)NB * PSTRIDE);         // 0.4 MB
    float* ald    = als + N;                                         // 0.4 MB
    int*   bcur   = (int*)(ald + N);                                 // NB
    unsigned short* bufH16 = (unsigned short*)(bcur + ((NB + 3) & ~3)); // 12.8 MB (16B-aligned)

    dim3 b256(256);
    int gInit = (NB + 255) / 256;
    int gPart = (E + EPB - 1) / EPB;
    int gGemm = (N + 63) / 64;

    // ---- bucket build: partition + per-bucket coarse src-sort --------------
    init_all<<<gInit, b256, 0, stream>>>(bcur, NB);
    partition<<<gPart, b256, 0, stream>>>(ei, E, NB, bcur, pairs);
    sort_bucket<<<NB, b256, 0, stream>>>(pairs, bcur, pairs2);

    // ---- layer 1 ----
    node_gemm<72><<<gGemm, b256, 0, stream>>>(x, W1, as1, ad1, nullptr, 0.0f,
                                              bufH16, als, ald, N);
    gat_aggregate2<<<NB, b256, 0, stream>>>(pairs2, bcur, als, ald, bufH16, bufO, N);

    // ---- layer 2 (input = leaky(bufO + b1, 0.01)) ----
    node_gemm<64><<<gGemm, b256, 0, stream>>>(bufO, W2, as2, ad2, b1, 0.01f,
                                              bufH16, als, ald, N);
    gat_aggregate2<<<NB, b256, 0, stream>>>(pairs2, bcur, als, ald, bufH16, bufO, N);

    // ---- fused pool + fc ----
    pool_fc<<<G, b256, 0, stream>>>(bufO, b2, batch, fcW, fcb, out, N);
}

// Round 2
// 341.336 us; speedup vs baseline: 4.6449x; 4.6449x over previous
//
#include <hip/hip_runtime.h>
#include <hip/hip_bf16.h>
#include <math.h>

// ---------------------------------------------------------------------------
// GAT: 2x GATConv(heads=1) + global mean pool + FC(64->2)
// R16 = R14 execution structure (proven 57.5us aggregate: register acc,
//       8 lanes/node, unroll-4, 32 VGPR, 8 blocks/CU) + R15's proven memory
//       ordering (src-sorted edge lists -> chip-wide convoy sweep of h16).
//   R15 post-mortem: sorted sweep DID cut FETCH 172->120MB, but LDS-atomic
//   accumulation + 33KB LDS (3 blocks/CU) + unroll-2 destroyed latency
//   hiding (VALU 1.8%, 693us). So: keep R14's gather kernel byte-identical,
//   change ONLY the order of edges within each node's CSR list via a
//   counting sort of each dst-bucket by src>>9 before build_csr.
//   Also: pairs/pairs2 alias onto bufO (disjoint lifetimes) -> ws ~46MB.
// ---------------------------------------------------------------------------

#define NPB 256          // nodes per bucket
#define EPB 4096         // edges per partition block (256 thr x 16)
#define PSTRIDE 4608     // slots per bucket (lambda=4092, +8 sigma)
#define XPAD 68          // xs leading-dim pad: 8-way banks, 16B-aligned rows

__device__ __forceinline__ unsigned int f2bf(float v) {
    unsigned int b = __float_as_uint(v);
    b += 0x7FFFu + ((b >> 16) & 1u);   // round-to-nearest-even
    return b >> 16;
}

// --- init: zero bucket cursors ----------------------------------------------
__global__ __launch_bounds__(256) void init_all(int* __restrict__ bcur, int NB) {
    int i = blockIdx.x * 256 + threadIdx.x;
    if (i < NB) bcur[i] = 0;
}

// --- partition edges into fixed-stride dst-buckets (packed uint32) ----------
__global__ __launch_bounds__(256) void partition(const int* __restrict__ ei,
                                                 int E, int NB,
                                                 int* __restrict__ bcur,
                                                 unsigned int* __restrict__ pairs) {
    __shared__ int h[512];
    __shared__ int hb[512];
    int t = threadIdx.x;
    for (int i = t; i < 512; i += 256) h[i] = 0;
    __syncthreads();
    int i0 = blockIdx.x * EPB;
    unsigned int val[16];
    int bk[16], r[16];
#pragma unroll
    for (int k = 0; k < 16; k++) {
        int i = i0 + k * 256 + t;
        bk[k] = -1;
        if (i < E) {
            int s = ei[i];
            int d = ei[E + i];
            bk[k] = d >> 8;
            val[k] = (unsigned)s | ((unsigned)(d & 255) << 24);
            r[k] = atomicAdd(&h[bk[k]], 1);
        }
    }
    __syncthreads();
    for (int b = t; b < NB; b += 256)
        hb[b] = h[b] ? atomicAdd(&bcur[b], h[b]) : 0;
    __syncthreads();
#pragma unroll
    for (int k = 0; k < 16; k++) {
        if (bk[k] < 0) continue;
        int pos = hb[bk[k]] + r[k];
        if (pos < PSTRIDE)                 // overflow guard (stat. impossible)
            pairs[(size_t)bk[k] * PSTRIDE + pos] = val[k];
    }
}

// --- coarse counting sort of each bucket's edges by src>>9 (512-node bins) --
// After build_csr's round-ordered fill, each node's CSR list is ~ascending
// in src. All co-resident aggregate blocks then sweep h16 through a moving
// window instead of randomly -> L2-hit rate up, L2-fill traffic down.
__global__ __launch_bounds__(256) void sort_bucket(const unsigned int* __restrict__ pairs,
                                                   const int* __restrict__ bcur,
                                                   unsigned int* __restrict__ pairs2) {
    int b = blockIdx.x, t = threadIdx.x;
    int cnt = min(bcur[b], PSTRIDE);
    __shared__ unsigned int Q[PSTRIDE];   // 18.4 KB
    __shared__ int hist[256];
    __shared__ int cur[256];
    hist[t] = 0;
    __syncthreads();
    const unsigned int* pb = pairs + (size_t)b * PSTRIDE;
    for (int j = t; j < cnt; j += 256)
        atomicAdd(&hist[(pb[j] & 0xFFFFFFu) >> 9], 1);   // key <= 195
    __syncthreads();
    int v = hist[t];
    cur[t] = v;
    __syncthreads();
    for (int o = 1; o < 256; o <<= 1) {
        int u = (t >= o) ? cur[t - o] : 0;
        __syncthreads();
        cur[t] += u;
        __syncthreads();
    }
    cur[t] -= v;                          // exclusive base -> cursor
    __syncthreads();
    for (int j = t; j < cnt; j += 256) {
        unsigned int p = pb[j];
        int pos = atomicAdd(&cur[(p & 0xFFFFFFu) >> 9], 1);
        Q[pos] = p;
    }
    __syncthreads();
    unsigned int* ob = pairs2 + (size_t)b * PSTRIDE;
    for (int j = t; j < cnt; j += 256) ob[j] = Q[j];     // coalesced
}

// --- per-bucket CSR fill; bucket-count scan inlined (each block rescans) ----
__global__ __launch_bounds__(256) void build_csr(const unsigned int* __restrict__ pairs,
                                                 const int* __restrict__ bcur,
                                                 int n, int NB,
                                                 int* __restrict__ rowptr,
                                                 int* __restrict__ srcs) {
    int b = blockIdx.x, t = threadIdx.x;
    __shared__ int c[512];
    __shared__ int s2[256];
    __shared__ int sbase, stot;
    int c0 = (2 * t < NB) ? min(bcur[2 * t], PSTRIDE) : 0;
    int c1 = (2 * t + 1 < NB) ? min(bcur[2 * t + 1], PSTRIDE) : 0;
    c[2 * t] = c0; c[2 * t + 1] = c1;
    s2[t] = c0 + c1;
    __syncthreads();
    for (int o = 1; o < 256; o <<= 1) {
        int u = (t >= o) ? s2[t - o] : 0;
        __syncthreads();
        s2[t] += u;
        __syncthreads();
    }
    if (t == 0) {
        int p = b >> 1;
        int ex = s2[p] - (c[2 * p] + c[2 * p + 1]);
        sbase = ex + ((b & 1) ? c[b & ~1] : 0);
        stot = s2[255];
    }
    __syncthreads();
    int d0 = b << 8;
    int nb = min(NPB, n - d0);
    int cnt_b = c[b];
    int csr0 = sbase + d0;   // pairs before + one self-loop per node before
    const unsigned int* pb = pairs + (size_t)b * PSTRIDE;

    __shared__ int deg[NPB];
    __shared__ int cur[NPB];
    __shared__ int tmp[NPB];
    deg[t] = (t < nb) ? 1 : 0;   // self-loop
    __syncthreads();
    for (int j = t; j < cnt_b; j += 256)
        atomicAdd(&deg[pb[j] >> 24], 1);
    __syncthreads();
    int v = deg[t];
    tmp[t] = v;
    __syncthreads();
    for (int o = 1; o < NPB; o <<= 1) {
        int u = (t >= o) ? tmp[t - o] : 0;
        __syncthreads();
        tmp[t] += u;
        __syncthreads();
    }
    int excl = tmp[t] - v;
    if (t < nb) {
        rowptr[d0 + t] = csr0 + excl;
        srcs[csr0 + excl] = d0 + t;   // self-loop at slot 0
        cur[t] = excl + 1;
    }
    __syncthreads();
    // scan in j-round order: since pairs is src-sorted, each node's list
    // fills ~ascending in src (rare intra-round swaps are harmless)
    for (int j = t; j < cnt_b; j += 256) {
        unsigned int p = pb[j];
        int off = atomicAdd(&cur[p >> 24], 1);
        srcs[csr0 + off] = (int)(p & 0x00FFFFFFu);
    }
    if (b == 0 && t == 0) rowptr[n] = n + stot;
}

// --- tiled node GEMM: 64 nodes x 64 cols per block, 4x4 per thread ----------
template <int IN_DIM>
__global__ __launch_bounds__(256) void node_gemm(const float* __restrict__ x,
                                                 const float* __restrict__ W,
                                                 const float* __restrict__ a_src,
                                                 const float* __restrict__ a_dst,
                                                 const float* __restrict__ bias_in,
                                                 float slope_in,
                                                 unsigned short* __restrict__ h16,
                                                 float* __restrict__ al_s,
                                                 float* __restrict__ al_d,
                                                 int n) {
    __shared__ float Ws[IN_DIM * 64];
    __shared__ float xs[IN_DIM][XPAD];
    int t = threadIdx.x;
    int nbase = blockIdx.x * 64;

    for (int idx = t; idx < IN_DIM * 16; idx += 256)
        ((float4*)Ws)[idx] = ((const float4*)W)[idx];
    const float* xb = x + (size_t)nbase * IN_DIM;
    int lim = min(64, n - nbase) * IN_DIM;
    for (int idx = t; idx < 64 * IN_DIM; idx += 256) {
        int node = idx / IN_DIM;
        int k = idx - node * IN_DIM;
        float v = 0.0f;
        if (idx < lim) {
            v = xb[idx];                       // contiguous, fully coalesced
            if (bias_in) {
                v += bias_in[k];
                v = (v >= 0.0f) ? v : slope_in * v;
            }
        }
        xs[k][node] = v;
    }
    __syncthreads();

    int cg = t & 15;    // col group: cols 4cg..4cg+3
    int ng = t >> 4;    // node group: nodes 4ng..4ng+3
    float acc[4][4] = {};
#pragma unroll 8
    for (int k = 0; k < IN_DIM; k++) {
        float4 xv = *(const float4*)&xs[k][ng * 4];
        float4 wv = *(const float4*)&Ws[k * 64 + cg * 4];
        float xa[4] = {xv.x, xv.y, xv.z, xv.w};
        float wa[4] = {wv.x, wv.y, wv.z, wv.w};
#pragma unroll
        for (int i = 0; i < 4; i++)
#pragma unroll
            for (int j = 0; j < 4; j++)
                acc[i][j] += xa[i] * wa[j];
    }

    float4 as4 = *(const float4*)(a_src + cg * 4);
    float4 ad4 = *(const float4*)(a_dst + cg * 4);
#pragma unroll
    for (int i = 0; i < 4; i++) {
        int node = nbase + ng * 4 + i;
        if (node < n) {
            uint2 p;
            p.x = f2bf(acc[i][0]) | (f2bf(acc[i][1]) << 16);
            p.y = f2bf(acc[i][2]) | (f2bf(acc[i][3]) << 16);
            *(uint2*)(h16 + (size_t)node * 64 + cg * 4) = p;
        }
        float vs = acc[i][0] * as4.x + acc[i][1] * as4.y +
                   acc[i][2] * as4.z + acc[i][3] * as4.w;
        float vd = acc[i][0] * ad4.x + acc[i][1] * ad4.y +
                   acc[i][2] * ad4.z + acc[i][3] * ad4.w;
#pragma unroll
        for (int o = 8; o; o >>= 1) {
            vs += __shfl_xor(vs, o);
            vd += __shfl_xor(vd, o);
        }
        if (cg == 0 && node < n) { al_s[node] = vs; al_d[node] = vd; }
    }
}

// --- single-pass aggregate (R6 proven body): 8 lanes/node, unroll x4 --------
// out[node] = (sum_j exp(e_j)*h[src_j]) / (sum_j exp(e_j) + 1e-16)
__device__ __forceinline__ void bf8_fma(float* acc, uint4 q, float w) {
    acc[0] += w * __uint_as_float(q.x << 16);
    acc[1] += w * __uint_as_float(q.x & 0xFFFF0000u);
    acc[2] += w * __uint_as_float(q.y << 16);
    acc[3] += w * __uint_as_float(q.y & 0xFFFF0000u);
    acc[4] += w * __uint_as_float(q.z << 16);
    acc[5] += w * __uint_as_float(q.z & 0xFFFF0000u);
    acc[6] += w * __uint_as_float(q.w << 16);
    acc[7] += w * __uint_as_float(q.w & 0xFFFF0000u);
}

__global__ __launch_bounds__(256) void gat_aggregate(const int* __restrict__ rowptr,
                                                     const int* __restrict__ srcs,
                                                     const float* __restrict__ als,
                                                     const float* __restrict__ ald,
                                                     const unsigned short* __restrict__ h16,
                                                     float* __restrict__ hout,
                                                     int n) {
    int t = threadIdx.x;
    int sub = t >> 3, lane = t & 7;       // 32 nodes/block, 8 lanes/node
    int node = blockIdx.x * 32 + sub;
    if (node >= n) return;
    int beg = rowptr[node], end = rowptr[node + 1];
    float aldv = ald[node];
    const unsigned short* hb = h16 + lane * 8;

    float acc[8] = {};
    float sm = 0.0f;
    int j = beg;
    for (; j + 4 <= end; j += 4) {
        int s0 = srcs[j], s1 = srcs[j + 1], s2 = srcs[j + 2], s3 = srcs[j + 3];
        float e0 = als[s0] + aldv, e1 = als[s1] + aldv;
        float e2 = als[s2] + aldv, e3 = als[s3] + aldv;
        uint4 q0 = *(const uint4*)(hb + (size_t)s0 * 64);
        uint4 q1 = *(const uint4*)(hb + (size_t)s1 * 64);
        uint4 q2 = *(const uint4*)(hb + (size_t)s2 * 64);
        uint4 q3 = *(const uint4*)(hb + (size_t)s3 * 64);
        e0 = (e0 >= 0.0f) ? e0 : 0.2f * e0;
        e1 = (e1 >= 0.0f) ? e1 : 0.2f * e1;
        e2 = (e2 >= 0.0f) ? e2 : 0.2f * e2;
        e3 = (e3 >= 0.0f) ? e3 : 0.2f * e3;
        float w0 = __expf(e0), w1 = __expf(e1);
        float w2 = __expf(e2), w3 = __expf(e3);
        sm += (w0 + w1) + (w2 + w3);
        bf8_fma(acc, q0, w0);
        bf8_fma(acc, q1, w1);
        bf8_fma(acc, q2, w2);
        bf8_fma(acc, q3, w3);
    }
    for (; j < end; j++) {
        int s = srcs[j];
        float e = als[s] + aldv;
        e = (e >= 0.0f) ? e : 0.2f * e;
        float w = __expf(e);
        uint4 q = *(const uint4*)(hb + (size_t)s * 64);
        sm += w;
        bf8_fma(acc, q, w);
    }

    float inv = 1.0f / (sm + 1e-16f);
    float4 o0 = make_float4(acc[0] * inv, acc[1] * inv, acc[2] * inv, acc[3] * inv);
    float4 o1 = make_float4(acc[4] * inv, acc[5] * inv, acc[6] * inv, acc[7] * inv);
    float* op = hout + (size_t)node * 64 + lane * 8;
    *(float4*)op = o0;
    *(float4*)(op + 4) = o1;
}

// --- fused pool + FC: one block per graph, binary-search batch bounds -------
__global__ __launch_bounds__(256) void pool_fc(const float* __restrict__ hout,
                                               const float* __restrict__ b2,
                                               const int* __restrict__ batch,
                                               const float* __restrict__ fcW,
                                               const float* __restrict__ fcb,
                                               float* __restrict__ out, int n) {
    int g = blockIdx.x;
    int t = threadIdx.x;
    __shared__ int sLo, sHi;
    __shared__ float red[4][64];
    if (t == 0) {
        int lo = 0, hi = n;
        while (lo < hi) { int m = (lo + hi) >> 1; if (batch[m] < g) lo = m + 1; else hi = m; }
        sLo = lo;
    } else if (t == 64) {
        int lo = 0, hi = n;
        while (lo < hi) { int m = (lo + hi) >> 1; if (batch[m] < g + 1) lo = m + 1; else hi = m; }
        sHi = lo;
    }
    __syncthreads();
    int lo = sLo, hi = sHi;
    int wv = t >> 6, lane = t & 63;
    float acc = 0.0f;
    for (int node = lo + wv; node < hi; node += 4)
        acc += hout[(size_t)node * 64 + lane];
    red[wv][lane] = acc;
    __syncthreads();
    if (wv == 0) {
        float c = (float)(hi - lo);
        float s = red[0][lane] + red[1][lane] + red[2][lane] + red[3][lane];
        s += c * b2[lane];
        float cd = (c > 1.0f) ? c : 1.0f;
        float p = s / cd;
        float s0 = p * fcW[lane * 2 + 0];
        float s1 = p * fcW[lane * 2 + 1];
#pragma unroll
        for (int o = 32; o; o >>= 1) {
            s0 += __shfl_xor(s0, o);
            s1 += __shfl_xor(s1, o);
        }
        if (lane == 0) {
            out[g * 2 + 0] = s0 + fcb[0];
            out[g * 2 + 1] = s1 + fcb[1];
        }
    }
}

extern "C" void kernel_launch(void* const* d_in, const int* in_sizes, int n_in,
                              void* d_out, int out_size, void* d_ws, size_t ws_size,
                              hipStream_t stream) {
    const float* x    = (const float*)d_in[0];
    const int*   ei   = (const int*)d_in[1];
    const int*   batch= (const int*)d_in[2];
    const float* W1   = (const float*)d_in[3];
    const float* as1  = (const float*)d_in[4];
    const float* ad1  = (const float*)d_in[5];
    const float* b1   = (const float*)d_in[6];
    const float* W2   = (const float*)d_in[7];
    const float* as2  = (const float*)d_in[8];
    const float* ad2  = (const float*)d_in[9];
    const float* b2   = (const float*)d_in[10];
    const float* fcW  = (const float*)d_in[11];
    const float* fcb  = (const float*)d_in[12];
    float* out = (float*)d_out;

    const int N = in_sizes[2];       // 100000
    const int E = in_sizes[1] / 2;   // 1600000
    const int G = out_size / 2;      // 256
    const int tot = E + N;
    const int NB = (N + NPB - 1) / NPB;   // 391 buckets

    // ws layout (~46 MiB): pairs/pairs2 ALIAS bufO (disjoint lifetimes:
    // pairs die at build_csr; bufO first written by aggregate layer 1).
    float* ws     = (float*)d_ws;
    float* bufO   = ws;                                  // N*64 fp32  25.6 MB
    unsigned int* pairs  = (unsigned int*)bufO;          // alias      7.2 MB
    unsigned int* pairs2 = pairs + (size_t)NB * PSTRIDE; // alias      7.2 MB
    float* als    = bufO + (size_t)N * 64;               // N          0.4 MB
    float* ald    = als + N;                             // N          0.4 MB
    int*   rowptr = (int*)(ald + N);                     // N+1        0.4 MB
    int*   srcs   = rowptr + N + 1;                      // tot        6.8 MB
    int*   bcur   = srcs + tot;                          // NB
    unsigned short* bufH16 = (unsigned short*)(bcur + NB);  // N*64   12.8 MB

    dim3 b256(256);
    int gInit = (NB + 255) / 256;
    int gPart = (E + EPB - 1) / EPB;
    int gGemm = (N + 63) / 64;
    int gAgg  = (N + 31) / 32;

    // ---- CSR build: partition + per-bucket src-sort + fill ------------------
    init_all<<<gInit, b256, 0, stream>>>(bcur, NB);
    partition<<<gPart, b256, 0, stream>>>(ei, E, NB, bcur, pairs);
    sort_bucket<<<NB, b256, 0, stream>>>(pairs, bcur, pairs2);
    build_csr<<<NB, b256, 0, stream>>>(pairs2, bcur, N, NB, rowptr, srcs);

    // ---- layer 1 ----
    node_gemm<72><<<gGemm, b256, 0, stream>>>(x, W1, as1, ad1, nullptr, 0.0f,
                                              bufH16, als, ald, N);
    gat_aggregate<<<gAgg, b256, 0, stream>>>(rowptr, srcs, als, ald, bufH16, bufO, N);

    // ---- layer 2 (input = leaky(bufO + b1, 0.01)) ----
    node_gemm<64><<<gGemm, b256, 0, stream>>>(bufO, W2, as2, ad2, b1, 0.01f,
                                              bufH16, als, ald, N);
    gat_aggregate<<<gAgg, b256, 0, stream>>>(rowptr, srcs, als, ald, bufH16, bufO, N);

    // ---- fused pool + fc ----
    pool_fc<<<G, b256, 0, stream>>>(bufO, b2, batch, fcW, fcb, out, N);
}

// Round 3
// 331.030 us; speedup vs baseline: 4.7895x; 1.0311x over previous
//
#include <hip/hip_runtime.h>
#include <hip/hip_bf16.h>
#include <math.h>

// ---------------------------------------------------------------------------
// GAT: 2x GATConv(heads=1) + global mean pool + FC(64->2)
// R17 = R16 minus its overhead, plus aggregate MLP pipeline.
//   R16 evidence: src-sorted CSR cut aggregate FETCH 172->155MB, dur
//   57.5->53.5us (dur ~ FETCH: L2-miss-path BW-bound at ~3.4TB/s). But
//   sort_bucket cost ~13us (pairs2 round-trip + launch) > 8us saved.
//   R17: (1) fuse counting sort INTO build_csr via LDS Q[PSTRIDE] --
//        sort_bucket kernel + pairs2 buffer deleted, same sorted CSR.
//        (2) aggregate: prefetch next quad's srcs indices one iteration
//        ahead (breaks srcs->gather serial chain; +~12 VGPR, <64 cliff).
// ---------------------------------------------------------------------------

#define NPB 256          // nodes per bucket
#define EPB 4096         // edges per partition block (256 thr x 16)
#define PSTRIDE 4608     // slots per bucket (lambda=4092, +8 sigma)
#define XPAD 68          // xs leading-dim pad: 8-way banks, 16B-aligned rows

__device__ __forceinline__ unsigned int f2bf(float v) {
    unsigned int b = __float_as_uint(v);
    b += 0x7FFFu + ((b >> 16) & 1u);   // round-to-nearest-even
    return b >> 16;
}

// --- init: zero bucket cursors ----------------------------------------------
__global__ __launch_bounds__(256) void init_all(int* __restrict__ bcur, int NB) {
    int i = blockIdx.x * 256 + threadIdx.x;
    if (i < NB) bcur[i] = 0;
}

// --- partition edges into fixed-stride dst-buckets (packed uint32) ----------
__global__ __launch_bounds__(256) void partition(const int* __restrict__ ei,
                                                 int E, int NB,
                                                 int* __restrict__ bcur,
                                                 unsigned int* __restrict__ pairs) {
    __shared__ int h[512];
    __shared__ int hb[512];
    int t = threadIdx.x;
    for (int i = t; i < 512; i += 256) h[i] = 0;
    __syncthreads();
    int i0 = blockIdx.x * EPB;
    unsigned int val[16];
    int bk[16], r[16];
#pragma unroll
    for (int k = 0; k < 16; k++) {
        int i = i0 + k * 256 + t;
        bk[k] = -1;
        if (i < E) {
            int s = ei[i];
            int d = ei[E + i];
            bk[k] = d >> 8;
            val[k] = (unsigned)s | ((unsigned)(d & 255) << 24);
            r[k] = atomicAdd(&h[bk[k]], 1);
        }
    }
    __syncthreads();
    for (int b = t; b < NB; b += 256)
        hb[b] = h[b] ? atomicAdd(&bcur[b], h[b]) : 0;
    __syncthreads();
#pragma unroll
    for (int k = 0; k < 16; k++) {
        if (bk[k] < 0) continue;
        int pos = hb[bk[k]] + r[k];
        if (pos < PSTRIDE)                 // overflow guard (stat. impossible)
            pairs[(size_t)bk[k] * PSTRIDE + pos] = val[k];
    }
}

// --- per-bucket CSR fill with FUSED counting sort by src>>9 -----------------
// Sort in LDS (Q), then degree/scan/fill directly from Q: no pairs2 buffer,
// no extra kernel. Each node's CSR list fills ~ascending in src, so all
// co-resident aggregate blocks sweep h16 through a moving window.
__global__ __launch_bounds__(256) void build_csr(const unsigned int* __restrict__ pairs,
                                                 const int* __restrict__ bcur,
                                                 int n, int NB,
                                                 int* __restrict__ rowptr,
                                                 int* __restrict__ srcs) {
    int b = blockIdx.x, t = threadIdx.x;
    __shared__ int c[512];
    __shared__ int s2[256];
    __shared__ int sbase, stot;
    __shared__ unsigned int Q[PSTRIDE];   // 18.4 KB sorted bucket
    __shared__ int hist[256];
    __shared__ int hcur[256];
    // ---- global bucket-count scan (for CSR base offset) ----
    int c0 = (2 * t < NB) ? min(bcur[2 * t], PSTRIDE) : 0;
    int c1 = (2 * t + 1 < NB) ? min(bcur[2 * t + 1], PSTRIDE) : 0;
    c[2 * t] = c0; c[2 * t + 1] = c1;
    s2[t] = c0 + c1;
    hist[t] = 0;
    __syncthreads();
    for (int o = 1; o < 256; o <<= 1) {
        int u = (t >= o) ? s2[t - o] : 0;
        __syncthreads();
        s2[t] += u;
        __syncthreads();
    }
    if (t == 0) {
        int p = b >> 1;
        int ex = s2[p] - (c[2 * p] + c[2 * p + 1]);
        sbase = ex + ((b & 1) ? c[b & ~1] : 0);
        stot = s2[255];
    }
    __syncthreads();
    int d0 = b << 8;
    int nb = min(NPB, n - d0);
    int cnt_b = c[b];
    int csr0 = sbase + d0;   // pairs before + one self-loop per node before
    const unsigned int* pb = pairs + (size_t)b * PSTRIDE;

    // ---- counting sort by src>>9 into Q ----
    for (int j = t; j < cnt_b; j += 256)
        atomicAdd(&hist[(pb[j] & 0xFFFFFFu) >> 9], 1);   // key <= 195
    __syncthreads();
    int hv = hist[t];
    hcur[t] = hv;
    __syncthreads();
    for (int o = 1; o < 256; o <<= 1) {
        int u = (t >= o) ? hcur[t - o] : 0;
        __syncthreads();
        hcur[t] += u;
        __syncthreads();
    }
    hcur[t] -= hv;                        // exclusive base -> cursor
    __syncthreads();
    for (int j = t; j < cnt_b; j += 256) {
        unsigned int p = pb[j];
        int pos = atomicAdd(&hcur[(p & 0xFFFFFFu) >> 9], 1);
        Q[pos] = p;
    }
    __syncthreads();

    // ---- degree count / scan / fill from sorted Q ----
    __shared__ int deg[NPB];
    __shared__ int cur[NPB];
    __shared__ int tmp[NPB];
    deg[t] = (t < nb) ? 1 : 0;   // self-loop
    __syncthreads();
    for (int j = t; j < cnt_b; j += 256)
        atomicAdd(&deg[Q[j] >> 24], 1);
    __syncthreads();
    int v = deg[t];
    tmp[t] = v;
    __syncthreads();
    for (int o = 1; o < NPB; o <<= 1) {
        int u = (t >= o) ? tmp[t - o] : 0;
        __syncthreads();
        tmp[t] += u;
        __syncthreads();
    }
    int excl = tmp[t] - v;
    if (t < nb) {
        rowptr[d0 + t] = csr0 + excl;
        srcs[csr0 + excl] = d0 + t;   // self-loop at slot 0
        cur[t] = excl + 1;
    }
    __syncthreads();
    // j-round order over sorted Q -> each node's list fills ~ascending in src
    for (int j = t; j < cnt_b; j += 256) {
        unsigned int p = Q[j];
        int off = atomicAdd(&cur[p >> 24], 1);
        srcs[csr0 + off] = (int)(p & 0x00FFFFFFu);
    }
    if (b == 0 && t == 0) rowptr[n] = n + stot;
}

// --- tiled node GEMM: 64 nodes x 64 cols per block, 4x4 per thread ----------
template <int IN_DIM>
__global__ __launch_bounds__(256) void node_gemm(const float* __restrict__ x,
                                                 const float* __restrict__ W,
                                                 const float* __restrict__ a_src,
                                                 const float* __restrict__ a_dst,
                                                 const float* __restrict__ bias_in,
                                                 float slope_in,
                                                 unsigned short* __restrict__ h16,
                                                 float* __restrict__ al_s,
                                                 float* __restrict__ al_d,
                                                 int n) {
    __shared__ float Ws[IN_DIM * 64];
    __shared__ float xs[IN_DIM][XPAD];
    int t = threadIdx.x;
    int nbase = blockIdx.x * 64;

    for (int idx = t; idx < IN_DIM * 16; idx += 256)
        ((float4*)Ws)[idx] = ((const float4*)W)[idx];
    const float* xb = x + (size_t)nbase * IN_DIM;
    int lim = min(64, n - nbase) * IN_DIM;
    for (int idx = t; idx < 64 * IN_DIM; idx += 256) {
        int node = idx / IN_DIM;
        int k = idx - node * IN_DIM;
        float v = 0.0f;
        if (idx < lim) {
            v = xb[idx];                       // contiguous, fully coalesced
            if (bias_in) {
                v += bias_in[k];
                v = (v >= 0.0f) ? v : slope_in * v;
            }
        }
        xs[k][node] = v;
    }
    __syncthreads();

    int cg = t & 15;    // col group: cols 4cg..4cg+3
    int ng = t >> 4;    // node group: nodes 4ng..4ng+3
    float acc[4][4] = {};
#pragma unroll 8
    for (int k = 0; k < IN_DIM; k++) {
        float4 xv = *(const float4*)&xs[k][ng * 4];
        float4 wv = *(const float4*)&Ws[k * 64 + cg * 4];
        float xa[4] = {xv.x, xv.y, xv.z, xv.w};
        float wa[4] = {wv.x, wv.y, wv.z, wv.w};
#pragma unroll
        for (int i = 0; i < 4; i++)
#pragma unroll
            for (int j = 0; j < 4; j++)
                acc[i][j] += xa[i] * wa[j];
    }

    float4 as4 = *(const float4*)(a_src + cg * 4);
    float4 ad4 = *(const float4*)(a_dst + cg * 4);
#pragma unroll
    for (int i = 0; i < 4; i++) {
        int node = nbase + ng * 4 + i;
        if (node < n) {
            uint2 p;
            p.x = f2bf(acc[i][0]) | (f2bf(acc[i][1]) << 16);
            p.y = f2bf(acc[i][2]) | (f2bf(acc[i][3]) << 16);
            *(uint2*)(h16 + (size_t)node * 64 + cg * 4) = p;
        }
        float vs = acc[i][0] * as4.x + acc[i][1] * as4.y +
                   acc[i][2] * as4.z + acc[i][3] * as4.w;
        float vd = acc[i][0] * ad4.x + acc[i][1] * ad4.y +
                   acc[i][2] * ad4.z + acc[i][3] * ad4.w;
#pragma unroll
        for (int o = 8; o; o >>= 1) {
            vs += __shfl_xor(vs, o);
            vd += __shfl_xor(vd, o);
        }
        if (cg == 0 && node < n) { al_s[node] = vs; al_d[node] = vd; }
    }
}

// --- single-pass aggregate: 8 lanes/node, unroll x4, srcs prefetch ----------
// out[node] = (sum_j exp(e_j)*h[src_j]) / (sum_j exp(e_j) + 1e-16)
__device__ __forceinline__ void bf8_fma(float* acc, uint4 q, float w) {
    acc[0] += w * __uint_as_float(q.x << 16);
    acc[1] += w * __uint_as_float(q.x & 0xFFFF0000u);
    acc[2] += w * __uint_as_float(q.y << 16);
    acc[3] += w * __uint_as_float(q.y & 0xFFFF0000u);
    acc[4] += w * __uint_as_float(q.z << 16);
    acc[5] += w * __uint_as_float(q.z & 0xFFFF0000u);
    acc[6] += w * __uint_as_float(q.w << 16);
    acc[7] += w * __uint_as_float(q.w & 0xFFFF0000u);
}

__global__ __launch_bounds__(256) void gat_aggregate(const int* __restrict__ rowptr,
                                                     const int* __restrict__ srcs,
                                                     const float* __restrict__ als,
                                                     const float* __restrict__ ald,
                                                     const unsigned short* __restrict__ h16,
                                                     float* __restrict__ hout,
                                                     int n) {
    int t = threadIdx.x;
    int sub = t >> 3, lane = t & 7;       // 32 nodes/block, 8 lanes/node
    int node = blockIdx.x * 32 + sub;
    if (node >= n) return;
    int beg = rowptr[node], end = rowptr[node + 1];
    float aldv = ald[node];
    const unsigned short* hb = h16 + lane * 8;

    float acc[8] = {};
    float sm = 0.0f;
    int j = beg;
    if (j + 4 <= end) {
        int s0 = srcs[j], s1 = srcs[j + 1], s2 = srcs[j + 2], s3 = srcs[j + 3];
        for (; j + 8 <= end; j += 4) {
            // prefetch next quad's indices: breaks srcs->gather serial chain
            int n0 = srcs[j + 4], n1 = srcs[j + 5];
            int n2 = srcs[j + 6], n3 = srcs[j + 7];
            float e0 = als[s0] + aldv, e1 = als[s1] + aldv;
            float e2 = als[s2] + aldv, e3 = als[s3] + aldv;
            uint4 q0 = *(const uint4*)(hb + (size_t)s0 * 64);
            uint4 q1 = *(const uint4*)(hb + (size_t)s1 * 64);
            uint4 q2 = *(const uint4*)(hb + (size_t)s2 * 64);
            uint4 q3 = *(const uint4*)(hb + (size_t)s3 * 64);
            e0 = (e0 >= 0.0f) ? e0 : 0.2f * e0;
            e1 = (e1 >= 0.0f) ? e1 : 0.2f * e1;
            e2 = (e2 >= 0.0f) ? e2 : 0.2f * e2;
            e3 = (e3 >= 0.0f) ? e3 : 0.2f * e3;
            float w0 = __expf(e0), w1 = __expf(e1);
            float w2 = __expf(e2), w3 = __expf(e3);
            sm += (w0 + w1) + (w2 + w3);
            bf8_fma(acc, q0, w0);
            bf8_fma(acc, q1, w1);
            bf8_fma(acc, q2, w2);
            bf8_fma(acc, q3, w3);
            s0 = n0; s1 = n1; s2 = n2; s3 = n3;
        }
        // final full quad (s0..s3 already loaded)
        {
            float e0 = als[s0] + aldv, e1 = als[s1] + aldv;
            float e2 = als[s2] + aldv, e3 = als[s3] + aldv;
            uint4 q0 = *(const uint4*)(hb + (size_t)s0 * 64);
            uint4 q1 = *(const uint4*)(hb + (size_t)s1 * 64);
            uint4 q2 = *(const uint4*)(hb + (size_t)s2 * 64);
            uint4 q3 = *(const uint4*)(hb + (size_t)s3 * 64);
            e0 = (e0 >= 0.0f) ? e0 : 0.2f * e0;
            e1 = (e1 >= 0.0f) ? e1 : 0.2f * e1;
            e2 = (e2 >= 0.0f) ? e2 : 0.2f * e2;
            e3 = (e3 >= 0.0f) ? e3 : 0.2f * e3;
            float w0 = __expf(e0), w1 = __expf(e1);
            float w2 = __expf(e2), w3 = __expf(e3);
            sm += (w0 + w1) + (w2 + w3);
            bf8_fma(acc, q0, w0);
            bf8_fma(acc, q1, w1);
            bf8_fma(acc, q2, w2);
            bf8_fma(acc, q3, w3);
            j += 4;
        }
    }
    for (; j < end; j++) {
        int s = srcs[j];
        float e = als[s] + aldv;
        e = (e >= 0.0f) ? e : 0.2f * e;
        float w = __expf(e);
        uint4 q = *(const uint4*)(hb + (size_t)s * 64);
        sm += w;
        bf8_fma(acc, q, w);
    }

    float inv = 1.0f / (sm + 1e-16f);
    float4 o0 = make_float4(acc[0] * inv, acc[1] * inv, acc[2] * inv, acc[3] * inv);
    float4 o1 = make_float4(acc[4] * inv, acc[5] * inv, acc[6] * inv, acc[7] * inv);
    float* op = hout + (size_t)node * 64 + lane * 8;
    *(float4*)op = o0;
    *(float4*)(op + 4) = o1;
}

// --- fused pool + FC: one block per graph, binary-search batch bounds -------
__global__ __launch_bounds__(256) void pool_fc(const float* __restrict__ hout,
                                               const float* __restrict__ b2,
                                               const int* __restrict__ batch,
                                               const float* __restrict__ fcW,
                                               const float* __restrict__ fcb,
                                               float* __restrict__ out, int n) {
    int g = blockIdx.x;
    int t = threadIdx.x;
    __shared__ int sLo, sHi;
    __shared__ float red[4][64];
    if (t == 0) {
        int lo = 0, hi = n;
        while (lo < hi) { int m = (lo + hi) >> 1; if (batch[m] < g) lo = m + 1; else hi = m; }
        sLo = lo;
    } else if (t == 64) {
        int lo = 0, hi = n;
        while (lo < hi) { int m = (lo + hi) >> 1; if (batch[m] < g + 1) lo = m + 1; else hi = m; }
        sHi = lo;
    }
    __syncthreads();
    int lo = sLo, hi = sHi;
    int wv = t >> 6, lane = t & 63;
    float acc = 0.0f;
    for (int node = lo + wv; node < hi; node += 4)
        acc += hout[(size_t)node * 64 + lane];
    red[wv][lane] = acc;
    __syncthreads();
    if (wv == 0) {
        float c = (float)(hi - lo);
        float s = red[0][lane] + red[1][lane] + red[2][lane] + red[3][lane];
        s += c * b2[lane];
        float cd = (c > 1.0f) ? c : 1.0f;
        float p = s / cd;
        float s0 = p * fcW[lane * 2 + 0];
        float s1 = p * fcW[lane * 2 + 1];
#pragma unroll
        for (int o = 32; o; o >>= 1) {
            s0 += __shfl_xor(s0, o);
            s1 += __shfl_xor(s1, o);
        }
        if (lane == 0) {
            out[g * 2 + 0] = s0 + fcb[0];
            out[g * 2 + 1] = s1 + fcb[1];
        }
    }
}

extern "C" void kernel_launch(void* const* d_in, const int* in_sizes, int n_in,
                              void* d_out, int out_size, void* d_ws, size_t ws_size,
                              hipStream_t stream) {
    const float* x    = (const float*)d_in[0];
    const int*   ei   = (const int*)d_in[1];
    const int*   batch= (const int*)d_in[2];
    const float* W1   = (const float*)d_in[3];
    const float* as1  = (const float*)d_in[4];
    const float* ad1  = (const float*)d_in[5];
    const float* b1   = (const float*)d_in[6];
    const float* W2   = (const float*)d_in[7];
    const float* as2  = (const float*)d_in[8];
    const float* ad2  = (const float*)d_in[9];
    const float* b2   = (const float*)d_in[10];
    const float* fcW  = (const float*)d_in[11];
    const float* fcb  = (const float*)d_in[12];
    float* out = (float*)d_out;

    const int N = in_sizes[2];       // 100000
    const int E = in_sizes[1] / 2;   // 1600000
    const int G = out_size / 2;      // 256
    const int tot = E + N;
    const int NB = (N + NPB - 1) / NPB;   // 391 buckets

    // ws layout (~46 MiB): pairs ALIASES bufO (disjoint lifetimes:
    // pairs die at build_csr; bufO first written by aggregate layer 1).
    float* ws     = (float*)d_ws;
    float* bufO   = ws;                                  // N*64 fp32  25.6 MB
    unsigned int* pairs  = (unsigned int*)bufO;          // alias      7.2 MB
    float* als    = bufO + (size_t)N * 64;               // N          0.4 MB
    float* ald    = als + N;                             // N          0.4 MB
    int*   rowptr = (int*)(ald + N);                     // N+1        0.4 MB
    int*   srcs   = rowptr + N + 1;                      // tot        6.8 MB
    int*   bcur   = srcs + tot;                          // NB
    unsigned short* bufH16 = (unsigned short*)(bcur + NB);  // N*64   12.8 MB

    dim3 b256(256);
    int gInit = (NB + 255) / 256;
    int gPart = (E + EPB - 1) / EPB;
    int gGemm = (N + 63) / 64;
    int gAgg  = (N + 31) / 32;

    // ---- CSR build: partition + fused sort/fill -----------------------------
    init_all<<<gInit, b256, 0, stream>>>(bcur, NB);
    partition<<<gPart, b256, 0, stream>>>(ei, E, NB, bcur, pairs);
    build_csr<<<NB, b256, 0, stream>>>(pairs, bcur, N, NB, rowptr, srcs);

    // ---- layer 1 ----
    node_gemm<72><<<gGemm, b256, 0, stream>>>(x, W1, as1, ad1, nullptr, 0.0f,
                                              bufH16, als, ald, N);
    gat_aggregate<<<gAgg, b256, 0, stream>>>(rowptr, srcs, als, ald, bufH16, bufO, N);

    // ---- layer 2 (input = leaky(bufO + b1, 0.01)) ----
    node_gemm<64><<<gGemm, b256, 0, stream>>>(bufO, W2, as2, ad2, b1, 0.01f,
                                              bufH16, als, ald, N);
    gat_aggregate<<<gAgg, b256, 0, stream>>>(rowptr, srcs, als, ald, bufH16, bufO, N);

    // ---- fused pool + fc ----
    pool_fc<<<G, b256, 0, stream>>>(bufO, b2, batch, fcW, fcb, out, N);
}